// Round 9
// baseline (281.292 us; speedup 1.0000x reference)
//
#include <hip/hip_runtime.h>
#include <math.h>

// ARAP loss: out[b] = mean_e | ||x[b,k]-x[b,j]||^2 - ||dx[b,k]-dx[b,j]||^2 |
//
//  1. transpose+fuse x,dx (B,NV,3) -> ct (NV,16,6): 24B record {x.xyz,dx.xyz};
//     16 batch records of a vertex = one contiguous 384B segment. Also zeroes
//     the cross-block counter used by step 3.
//  2. main: per 64-lane wave, one contiguous span; ballot-compact j<k
//     survivors (mirrors bit-identical -> weight 2) into wave-private LDS,
//     pad to x16 with (0,0) dummies; each 16-lane group (lane b = t&15)
//     walks its quarter 8 edges/step = 48 dwordx2 in flight/lane.
//     MEASURED CEILING: ~59us = ~119MB L2-miss traffic at ~2.05TB/s random-
//     line service rate (invariant across 2x occupancy/MLP -> throughput-
//     bound, not concurrency-bound). Don't churn this.
//  3. finalize fused into main: threadfence + atomicAdd; last block reduces
//     the 1024x16 partials in double and writes out[b]. One fewer dispatch.

#define THREADS 256
#define MAIN_BLOCKS 1024
#define NWAVES (MAIN_BLOCKS * 4)
#define CHUNK 256               // edges per compaction chunk
#define TTV 32                  // vertices per transpose block

// ---------- transpose+fuse (B,NV,3) x2 -> (NV,16,6), float4 stores ----------
__global__ __launch_bounds__(256) void arap_transpose(
        const float* __restrict__ x, const float* __restrict__ dx,
        float* __restrict__ ct, unsigned* __restrict__ ctr, int NV) {
    if (blockIdx.x == 0 && threadIdx.x == 0) *ctr = 0;   // for main's last-block
    __shared__ float tile[TTV * 100];   // row 100 floats: 16B-aligned rows
    int t  = threadIdx.x;
    int v0 = blockIdx.x * TTV;
    int bb = t >> 4, vb = t & 15;
    #pragma unroll
    for (int vi = 0; vi < 2; ++vi) {
        int vloc = vi * 16 + vb;
        int v = v0 + vloc;
        if (v < NV) {
            const float* px  = x  + ((size_t)bb * NV + v) * 3;
            const float* pdx = dx + ((size_t)bb * NV + v) * 3;
            float a0 = px[0],  a1 = px[1],  a2 = px[2];
            float b0 = pdx[0], b1 = pdx[1], b2 = pdx[2];
            float* tr = tile + vloc * 100 + bb * 6;
            tr[0] = a0; tr[1] = a1; tr[2] = a2;
            tr[3] = b0; tr[4] = b1; tr[5] = b2;
        }
    }
    __syncthreads();
    if (v0 + TTV <= NV) {               // full tile: 3 float4 per thread
        float4* outv = (float4*)(ct + (size_t)v0 * 96);
        #pragma unroll
        for (int i = 0; i < 3; ++i) {
            int f = t * 3 + i;          // float4 index 0..767
            int o = f * 4;              // float offset
            int v = o / 96, r = o - v * 96;
            const float* ts = tile + v * 100 + r;   // 16B-aligned
            outv[f] = make_float4(ts[0], ts[1], ts[2], ts[3]);
        }
    } else {                            // tail tile
        #pragma unroll
        for (int i = 0; i < 3; ++i) {
            int f = t * 3 + i, o = f * 4;
            int v = o / 96, r = o - v * 96;
            if (v0 + v < NV) {
                float* dst = ct + (size_t)(v0 + v) * 96 + r;
                const float* ts = tile + v * 100 + r;
                dst[0] = ts[0]; dst[1] = ts[1]; dst[2] = ts[2]; dst[3] = ts[3];
            }
        }
    }
}

// record pointer for vertex v (batch baked into vbase)
#define RP(v) ((const float2*)(vbase + (size_t)(v) * 96))
// load 4 edges (8 records = 24 float2) from compacted indices S..S+3
#define LOAD4(R, S) { \
    int2 Ea = cbuf[wv][S], Eb = cbuf[wv][(S)+1], Ec = cbuf[wv][(S)+2], Ed = cbuf[wv][(S)+3]; \
    const float2 *ja=RP(Ea.x),*ka=RP(Ea.y),*jb=RP(Eb.x),*kb=RP(Eb.y); \
    const float2 *jc=RP(Ec.x),*kc=RP(Ec.y),*jd=RP(Ed.x),*kd=RP(Ed.y); \
    R[0]=ja[0];  R[1]=ja[1];  R[2]=ja[2];  R[3]=ka[0];  R[4]=ka[1];  R[5]=ka[2]; \
    R[6]=jb[0];  R[7]=jb[1];  R[8]=jb[2];  R[9]=kb[0];  R[10]=kb[1]; R[11]=kb[2]; \
    R[12]=jc[0]; R[13]=jc[1]; R[14]=jc[2]; R[15]=kc[0]; R[16]=kc[1]; R[17]=kc[2]; \
    R[18]=jd[0]; R[19]=jd[1]; R[20]=jd[2]; R[21]=kd[0]; R[22]=kd[1]; R[23]=kd[2]; }
// |e|^2-|f|^2 term from records j=(J0,J1,J2), k=(K0,K1,K2)
#define EV1(J0,J1,J2,K0,K1,K2) ({ \
    float _ex=K0.x-J0.x, _ey=K0.y-J0.y, _ez=K1.x-J1.x; \
    float _fx=K1.y-J1.y, _fy=K2.x-J2.x, _fz=K2.y-J2.y; \
    fabsf((_ex*_ex+_ey*_ey+_ez*_ez)-(_fx*_fx+_fy*_fy+_fz*_fz)); })
#define COMP4(R) ((EV1(R[0],R[1],R[2],R[3],R[4],R[5]) + EV1(R[6],R[7],R[8],R[9],R[10],R[11])) + \
                  (EV1(R[12],R[13],R[14],R[15],R[16],R[17]) + EV1(R[18],R[19],R[20],R[21],R[22],R[23])))

// ---------- main: compaction + deep-MLP gather + fused last-block finalize ----------
__global__ __launch_bounds__(256, 4) void arap_main_fused(
        const float* __restrict__ ct, const int2* __restrict__ edges,
        float* __restrict__ partial, unsigned* __restrict__ ctr,
        float* __restrict__ out, long E, long spw, double scale) {
    __shared__ int2   cbuf[4][CHUNK + 16];
    __shared__ float  sacc[4][16];
    __shared__ double dacc[16][17];
    __shared__ int    amLastSh;
    int t = threadIdx.x, lane = t & 63, wv = t >> 6, b = t & 15, sg = (t >> 4) & 3;
    // XCD swizzle: each XCD owns a contiguous 1/8 of the edge list
    int sbid = (blockIdx.x & 7) * (MAIN_BLOCKS / 8) + (blockIdx.x >> 3);
    long wid = (long)sbid * 4 + wv;
    long e0 = wid * spw;
    long e1 = e0 + spw; if (e1 > E) e1 = E;
    const float* vbase = ct + b * 6;
    float acc = 0.f;

    for (long cbase = e0; cbase < e1; cbase += CHUNK) {
        int cnt = (int)((e1 - cbase < CHUNK) ? (e1 - cbase) : CHUNK);
        // --- load 4 edges/lane (spw%4==0 -> 16B-aligned int4) ---
        long eidx = cbase + 4 * lane;
        int base4 = 4 * lane;
        int4 qa = make_int4(0,0,0,0), qb = make_int4(0,0,0,0);
        if (base4 + 3 < cnt) {
            qa = *(const int4*)(&edges[eidx]);
            qb = *(const int4*)(&edges[eidx + 2]);
        } else if (base4 < cnt) {
            int2 t0 = edges[eidx];
            int2 t1 = (base4+1 < cnt) ? edges[eidx+1] : make_int2(0,0);
            int2 t2 = (base4+2 < cnt) ? edges[eidx+2] : make_int2(0,0);
            qa = make_int4(t0.x, t0.y, t1.x, t1.y);
            qb = make_int4(t2.x, t2.y, 0, 0);
        }
        // --- ballot rank-compact j<k survivors ---
        bool p0 = (base4+0 < cnt) && (qa.x < qa.y);
        bool p1 = (base4+1 < cnt) && (qa.z < qa.w);
        bool p2 = (base4+2 < cnt) && (qb.x < qb.y);
        bool p3 = (base4+3 < cnt) && (qb.z < qb.w);
        unsigned long long m0 = __ballot(p0), m1 = __ballot(p1);
        unsigned long long m2 = __ballot(p2), m3 = __ballot(p3);
        unsigned long long pre = ((unsigned long long)1 << lane) - 1;
        int c0 = __popcll(m0), c1 = c0 + __popcll(m1), c2 = c1 + __popcll(m2);
        int npass = c2 + __popcll(m3);
        if (p0) cbuf[wv][     __popcll(m0 & pre)] = make_int2(qa.x, qa.y);
        if (p1) cbuf[wv][c0 + __popcll(m1 & pre)] = make_int2(qa.z, qa.w);
        if (p2) cbuf[wv][c1 + __popcll(m2 & pre)] = make_int2(qb.x, qb.y);
        if (p3) cbuf[wv][c2 + __popcll(m3 & pre)] = make_int2(qb.z, qb.w);
        // pad to multiple of 16 with (0,0): contributes exactly 0
        int npad = (npass + 15) & ~15;
        if (lane < npad - npass) cbuf[wv][npass + lane] = make_int2(0, 0);
        // (no barrier: cbuf is wave-private)

        // --- each group: contiguous quarter, 8 edges per step ---
        int npg  = npad >> 2;
        int gbeg = sg * npg, gend = gbeg + npg;
        float2 A[24], Bst[24];
        for (int s = gbeg; s < gend; s += 8) {
            LOAD4(A, s);
            bool hasB = (s + 4 < gend);          // wave-uniform
            if (hasB) LOAD4(Bst, s + 4);
            acc += COMP4(A);
            if (hasB) acc += COMP4(Bst);
        }
    }

    // fold the 4 groups of this wave onto lanes 0-15 (one per b)
    acc += __shfl_xor(acc, 16, 64);
    acc += __shfl_xor(acc, 32, 64);
    if (lane < 16) sacc[wv][lane] = acc;
    __syncthreads();
    if (t < 16) {
        float s = 0.f;
        #pragma unroll
        for (int w = 0; w < 4; ++w) s += sacc[w][t];
        partial[(size_t)blockIdx.x * 16 + t] = s;
    }
    // --- last-block finalize ---
    __threadfence();                 // make partial[] device-visible
    __syncthreads();                 // all lanes fenced before the ticket
    if (t == 0) amLastSh = (atomicAdd(ctr, 1u) == gridDim.x - 1);
    __syncthreads();
    if (amLastSh) {
        __threadfence();             // acquire side
        int r0 = t >> 4;
        double s = 0.0;
        for (int i = r0; i < MAIN_BLOCKS; i += 16)
            s += (double)partial[(size_t)i * 16 + b];
        dacc[r0][b] = s;
        __syncthreads();
        if (t < 16) {
            double tot = 0.0;
            #pragma unroll
            for (int r = 0; r < 16; ++r) tot += dacc[r][t];
            out[t] = (float)(tot * scale);
        }
    }
}

// ---------- fallback: direct gather from (B,NV,3), j<k, chunked ----------
__global__ void arap_main_generic(const float* __restrict__ X,
                                  const float* __restrict__ DX,
                                  const int2* __restrict__ edges,
                                  float* __restrict__ partial,
                                  long E, int chunk, int NV, int B) {
    int t = threadIdx.x;
    int b = t & 15;
    int g = blockIdx.x * (THREADS / 16) + (t >> 4);
    long e0 = (long)g * chunk;
    long e1 = e0 + chunk; if (e1 > E) e1 = E;
    size_t boff = (size_t)b * NV * 3;
    float acc = 0.f;
    if (b < B) {
        for (long e = e0; e < e1; ++e) {
            int2 jk = edges[e];
            if (jk.x < jk.y) {
                size_t aj = boff + (size_t)jk.x * 3, ak = boff + (size_t)jk.y * 3;
                float ex = X[ak] - X[aj], ey = X[ak+1] - X[aj+1], ez = X[ak+2] - X[aj+2];
                float fx = DX[ak] - DX[aj], fy = DX[ak+1] - DX[aj+1], fz = DX[ak+2] - DX[aj+2];
                acc += fabsf((ex*ex + ey*ey + ez*ez) - (fx*fx + fy*fy + fz*fz));
            }
        }
    }
    acc += __shfl_xor(acc, 16, 64);
    acc += __shfl_xor(acc, 32, 64);
    __shared__ float sacc[THREADS / 64][16];
    int wave = t >> 6, lane = t & 63;
    if (lane < 16) sacc[wave][lane] = acc;
    __syncthreads();
    if (t < 16) {
        float s = 0.f;
        #pragma unroll
        for (int w = 0; w < THREADS / 64; ++w) s += sacc[w][t];
        partial[(size_t)blockIdx.x * 16 + t] = s;
    }
}

// ---------- standalone finalize (fallback path only) ----------
__global__ void arap_finalize(const float* __restrict__ partial,
                              float* __restrict__ out, int NB, double scale) {
    int b = blockIdx.x;
    int t = threadIdx.x;
    double s = 0.0;
    for (int i = t; i < NB; i += blockDim.x)
        s += (double)partial[(size_t)i * 16 + b];
    #pragma unroll
    for (int off = 32; off; off >>= 1) s += __shfl_xor(s, off, 64);
    __shared__ double ws_[THREADS / 64];
    int wave = t >> 6, lane = t & 63;
    if (lane == 0) ws_[wave] = s;
    __syncthreads();
    if (t == 0) {
        double tot = 0.0;
        #pragma unroll
        for (int w = 0; w < THREADS / 64; ++w) tot += ws_[w];
        out[b] = (float)(tot * scale);
    }
}

extern "C" void kernel_launch(void* const* d_in, const int* in_sizes, int n_in,
                              void* d_out, int out_size, void* d_ws, size_t ws_size,
                              hipStream_t stream) {
    const float* dx    = (const float*)d_in[0];   // (B, NV, 3)
    const float* x     = (const float*)d_in[1];   // (B, NV, 3)
    const int*   edges = (const int*)d_in[2];     // (E, 2), sorted, symmetric
    float* out = (float*)d_out;

    int B   = out_size;                 // 16
    long E  = in_sizes[2] / 2;
    int NV  = in_sizes[0] / (B * 3);    // 100000

    // per-wave span, multiple of 4 (keeps int4 edge loads 16B-aligned)
    long spw = (E + NWAVES - 1) / NWAVES;
    spw = (spw + 3) & ~(long)3;

    // ws layout: [ctr 256B][partial][ct]
    size_t ctr_bytes     = 256;
    size_t partial_bytes = ((size_t)MAIN_BLOCKS * 16 * sizeof(float) + 255) & ~(size_t)255;
    size_t ct_bytes      = (size_t)NV * 16 * 6 * sizeof(float);

    unsigned* ctrp  = (unsigned*)d_ws;
    float* partial  = (float*)((char*)d_ws + ctr_bytes);
    double scale = 2.0 / (double)E;     // j<k only; mirrors are bit-identical

    if (B == 16 && ws_size >= ctr_bytes + partial_bytes + ct_bytes) {
        float* ct = (float*)((char*)d_ws + ctr_bytes + partial_bytes);
        arap_transpose<<<(NV + TTV - 1) / TTV, THREADS, 0, stream>>>(x, dx, ct, ctrp, NV);
        arap_main_fused<<<MAIN_BLOCKS, THREADS, 0, stream>>>(ct, (const int2*)edges,
                                                             partial, ctrp, out,
                                                             E, spw, scale);
    } else {
        int ggrid = 2048;
        int chunk = (int)((E + (long)ggrid * 16 - 1) / ((long)ggrid * 16));
        arap_main_generic<<<ggrid, THREADS, 0, stream>>>(x, dx, (const int2*)edges,
                                                         partial, E, chunk, NV, B);
        arap_finalize<<<B, THREADS, 0, stream>>>(partial, out, ggrid, scale);
    }
}

// Round 13
// 152.266 us; speedup vs baseline: 1.8474x; 1.8474x over previous
//
#include <hip/hip_runtime.h>
#include <math.h>

// ARAP loss: out[b] = mean_e | ||x[b,k]-x[b,j]||^2 - ||dx[b,k]-dx[b,j]||^2 |
//
//  1. transpose+fuse x,dx (B,NV,3) -> ct (NV,16,6): 24B record {x.xyz,dx.xyz};
//     16 batch records of a vertex = one contiguous 384B segment.
//     float4 global reads (batch-row bases 16B-aligned) + float4 writes.
//  2. main: per 64-lane wave, one contiguous span; ballot-compact j<k
//     survivors (mirrors bit-identical -> weight 2) into wave-private LDS,
//     pad to x16 with (0,0) dummies; each 16-lane group (lane b = t&15)
//     walks its quarter 8 edges/step = 48 dwordx2 in flight/lane.
//     MEASURED CEILING: ~59us = ~119MB L2-miss traffic at ~2.05TB/s random-
//     line service rate (invariant across 2x occupancy/MLP). Don't churn.
//  3. finalize: SEPARATE tiny kernel. MEASURED (r9): fusing it last-block
//     style with __threadfence+atomicAdd inside main tripled main's time
//     (59->193us, same FETCH) -- device-scope fence per wave wrecks the
//     whole memory pipeline on non-coherent-L2 CDNA4. Never fuse it.

#define THREADS 256
#define MAIN_BLOCKS 1024
#define NWAVES (MAIN_BLOCKS * 4)
#define CHUNK 256               // edges per compaction chunk
#define TTV 64                  // vertices per transpose block

// ---------- transpose+fuse (B,NV,3) x2 -> (NV,16,6), float4 both sides ----------
__global__ __launch_bounds__(256) void arap_transpose(
        const float* __restrict__ x, const float* __restrict__ dx,
        float* __restrict__ ct, int NV) {
    __shared__ float tile[TTV * 100];   // [v][b*6+c], row 100 floats (16B-aligned rows)
    int t  = threadIdx.x;
    int v0 = blockIdx.x * TTV;
    int bb = t >> 4, vb = t & 15;
    size_t NV3 = (size_t)NV * 3;

    if (v0 + TTV <= NV) {
        // fast phase-1: row base b*NV3 + v0*3 is 16B-aligned (NV3*4 % 16 == 0, v0%64==0)
        const float4* xr = (const float4*)(x  + (size_t)bb * NV3 + (size_t)v0 * 3);
        const float4* dr = (const float4*)(dx + (size_t)bb * NV3 + (size_t)v0 * 3);
        #pragma unroll
        for (int i = 0; i < 3; ++i) {
            float4 qx = xr[vb * 3 + i];
            float4 qd = dr[vb * 3 + i];
            const float* px = &qx.x;
            const float* pd = &qd.x;
            #pragma unroll
            for (int l = 0; l < 4; ++l) {
                int ff   = i * 4 + l;            // 0..11, compile-time
                int vloc = vb * 4 + ff / 3;      // vertex in tile
                int c    = ff % 3;               // component
                tile[vloc * 100 + bb * 6 + c]     = px[l];
                tile[vloc * 100 + bb * 6 + 3 + c] = pd[l];
            }
        }
    } else {
        // tail tile: scalar per-(b,v) records with guard
        #pragma unroll
        for (int vi = 0; vi < TTV / 16; ++vi) {
            int vloc = vi * 16 + vb;
            int v = v0 + vloc;
            if (v < NV) {
                const float* px  = x  + (size_t)bb * NV3 + (size_t)v * 3;
                const float* pdx = dx + (size_t)bb * NV3 + (size_t)v * 3;
                float* tr = tile + vloc * 100 + bb * 6;
                tr[0] = px[0];  tr[1] = px[1];  tr[2] = px[2];
                tr[3] = pdx[0]; tr[4] = pdx[1]; tr[5] = pdx[2];
            }
        }
    }
    __syncthreads();
    if (v0 + TTV <= NV) {
        // phase-2: 1536 float4 per tile, 6 per thread, f = i*256+t coalesced
        float4* outv = (float4*)(ct + (size_t)v0 * 96);
        #pragma unroll
        for (int i = 0; i < 6; ++i) {
            int f = i * 256 + t;
            int v = f / 24, r4 = (f % 24) * 4;
            outv[f] = *(const float4*)(tile + v * 100 + r4);   // 16B-aligned LDS read
        }
    } else {
        #pragma unroll
        for (int i = 0; i < 6; ++i) {
            int f = i * 256 + t;
            int v = f / 24, r4 = (f % 24) * 4;
            if (v0 + v < NV) {
                float* dst = ct + (size_t)(v0 + v) * 96 + r4;
                const float* ts = tile + v * 100 + r4;
                dst[0] = ts[0]; dst[1] = ts[1]; dst[2] = ts[2]; dst[3] = ts[3];
            }
        }
    }
}

// record pointer for vertex v (batch baked into vbase)
#define RP(v) ((const float2*)(vbase + (size_t)(v) * 96))
// load 4 edges (8 records = 24 float2) from compacted indices S..S+3
#define LOAD4(R, S) { \
    int2 Ea = cbuf[wv][S], Eb = cbuf[wv][(S)+1], Ec = cbuf[wv][(S)+2], Ed = cbuf[wv][(S)+3]; \
    const float2 *ja=RP(Ea.x),*ka=RP(Ea.y),*jb=RP(Eb.x),*kb=RP(Eb.y); \
    const float2 *jc=RP(Ec.x),*kc=RP(Ec.y),*jd=RP(Ed.x),*kd=RP(Ed.y); \
    R[0]=ja[0];  R[1]=ja[1];  R[2]=ja[2];  R[3]=ka[0];  R[4]=ka[1];  R[5]=ka[2]; \
    R[6]=jb[0];  R[7]=jb[1];  R[8]=jb[2];  R[9]=kb[0];  R[10]=kb[1]; R[11]=kb[2]; \
    R[12]=jc[0]; R[13]=jc[1]; R[14]=jc[2]; R[15]=kc[0]; R[16]=kc[1]; R[17]=kc[2]; \
    R[18]=jd[0]; R[19]=jd[1]; R[20]=jd[2]; R[21]=kd[0]; R[22]=kd[1]; R[23]=kd[2]; }
// |e|^2-|f|^2 term from records j=(J0,J1,J2), k=(K0,K1,K2)
#define EV1(J0,J1,J2,K0,K1,K2) ({ \
    float _ex=K0.x-J0.x, _ey=K0.y-J0.y, _ez=K1.x-J1.x; \
    float _fx=K1.y-J1.y, _fy=K2.x-J2.x, _fz=K2.y-J2.y; \
    fabsf((_ex*_ex+_ey*_ey+_ez*_ez)-(_fx*_fx+_fy*_fy+_fz*_fz)); })
#define COMP4(R) ((EV1(R[0],R[1],R[2],R[3],R[4],R[5]) + EV1(R[6],R[7],R[8],R[9],R[10],R[11])) + \
                  (EV1(R[12],R[13],R[14],R[15],R[16],R[17]) + EV1(R[18],R[19],R[20],R[21],R[22],R[23])))

// ---------- main: compaction + deep-MLP gather (round-5 measured version) ----------
__global__ __launch_bounds__(256, 4) void arap_main_fused(
        const float* __restrict__ ct, const int2* __restrict__ edges,
        float* __restrict__ partial, long E, long spw) {
    __shared__ int2  cbuf[4][CHUNK + 16];
    __shared__ float sacc[4][16];
    int t = threadIdx.x, lane = t & 63, wv = t >> 6, b = t & 15, sg = (t >> 4) & 3;
    // XCD swizzle: each XCD owns a contiguous 1/8 of the edge list
    int sbid = (blockIdx.x & 7) * (MAIN_BLOCKS / 8) + (blockIdx.x >> 3);
    long wid = (long)sbid * 4 + wv;
    long e0 = wid * spw;
    long e1 = e0 + spw; if (e1 > E) e1 = E;
    const float* vbase = ct + b * 6;
    float acc = 0.f;

    for (long cbase = e0; cbase < e1; cbase += CHUNK) {
        int cnt = (int)((e1 - cbase < CHUNK) ? (e1 - cbase) : CHUNK);
        // --- load 4 edges/lane (spw%4==0 -> 16B-aligned int4) ---
        long eidx = cbase + 4 * lane;
        int base4 = 4 * lane;
        int4 qa = make_int4(0,0,0,0), qb = make_int4(0,0,0,0);
        if (base4 + 3 < cnt) {
            qa = *(const int4*)(&edges[eidx]);
            qb = *(const int4*)(&edges[eidx + 2]);
        } else if (base4 < cnt) {
            int2 t0 = edges[eidx];
            int2 t1 = (base4+1 < cnt) ? edges[eidx+1] : make_int2(0,0);
            int2 t2 = (base4+2 < cnt) ? edges[eidx+2] : make_int2(0,0);
            qa = make_int4(t0.x, t0.y, t1.x, t1.y);
            qb = make_int4(t2.x, t2.y, 0, 0);
        }
        // --- ballot rank-compact j<k survivors ---
        bool p0 = (base4+0 < cnt) && (qa.x < qa.y);
        bool p1 = (base4+1 < cnt) && (qa.z < qa.w);
        bool p2 = (base4+2 < cnt) && (qb.x < qb.y);
        bool p3 = (base4+3 < cnt) && (qb.z < qb.w);
        unsigned long long m0 = __ballot(p0), m1 = __ballot(p1);
        unsigned long long m2 = __ballot(p2), m3 = __ballot(p3);
        unsigned long long pre = ((unsigned long long)1 << lane) - 1;
        int c0 = __popcll(m0), c1 = c0 + __popcll(m1), c2 = c1 + __popcll(m2);
        int npass = c2 + __popcll(m3);
        if (p0) cbuf[wv][     __popcll(m0 & pre)] = make_int2(qa.x, qa.y);
        if (p1) cbuf[wv][c0 + __popcll(m1 & pre)] = make_int2(qa.z, qa.w);
        if (p2) cbuf[wv][c1 + __popcll(m2 & pre)] = make_int2(qb.x, qb.y);
        if (p3) cbuf[wv][c2 + __popcll(m3 & pre)] = make_int2(qb.z, qb.w);
        // pad to multiple of 16 with (0,0): contributes exactly 0
        int npad = (npass + 15) & ~15;
        if (lane < npad - npass) cbuf[wv][npass + lane] = make_int2(0, 0);
        // (no barrier: cbuf is wave-private)

        // --- each group: contiguous quarter, 8 edges per step ---
        int npg  = npad >> 2;
        int gbeg = sg * npg, gend = gbeg + npg;
        float2 A[24], Bst[24];
        for (int s = gbeg; s < gend; s += 8) {
            LOAD4(A, s);
            bool hasB = (s + 4 < gend);          // wave-uniform
            if (hasB) LOAD4(Bst, s + 4);
            acc += COMP4(A);
            if (hasB) acc += COMP4(Bst);
        }
    }

    // fold the 4 groups of this wave onto lanes 0-15 (one per b)
    acc += __shfl_xor(acc, 16, 64);
    acc += __shfl_xor(acc, 32, 64);
    if (lane < 16) sacc[wv][lane] = acc;
    __syncthreads();
    if (t < 16) {
        float s = 0.f;
        #pragma unroll
        for (int w = 0; w < 4; ++w) s += sacc[w][t];
        partial[(size_t)blockIdx.x * 16 + t] = s;
    }
}

// ---------- fallback: direct gather from (B,NV,3), j<k, chunked ----------
__global__ void arap_main_generic(const float* __restrict__ X,
                                  const float* __restrict__ DX,
                                  const int2* __restrict__ edges,
                                  float* __restrict__ partial,
                                  long E, int chunk, int NV, int B) {
    int t = threadIdx.x;
    int b = t & 15;
    int g = blockIdx.x * (THREADS / 16) + (t >> 4);
    long e0 = (long)g * chunk;
    long e1 = e0 + chunk; if (e1 > E) e1 = E;
    size_t boff = (size_t)b * NV * 3;
    float acc = 0.f;
    if (b < B) {
        for (long e = e0; e < e1; ++e) {
            int2 jk = edges[e];
            if (jk.x < jk.y) {
                size_t aj = boff + (size_t)jk.x * 3, ak = boff + (size_t)jk.y * 3;
                float ex = X[ak] - X[aj], ey = X[ak+1] - X[aj+1], ez = X[ak+2] - X[aj+2];
                float fx = DX[ak] - DX[aj], fy = DX[ak+1] - DX[aj+1], fz = DX[ak+2] - DX[aj+2];
                acc += fabsf((ex*ex + ey*ey + ez*ez) - (fx*fx + fy*fy + fz*fz));
            }
        }
    }
    acc += __shfl_xor(acc, 16, 64);
    acc += __shfl_xor(acc, 32, 64);
    __shared__ float sacc[THREADS / 64][16];
    int wave = t >> 6, lane = t & 63;
    if (lane < 16) sacc[wave][lane] = acc;
    __syncthreads();
    if (t < 16) {
        float s = 0.f;
        #pragma unroll
        for (int w = 0; w < THREADS / 64; ++w) s += sacc[w][t];
        partial[(size_t)blockIdx.x * 16 + t] = s;
    }
}

// ---------- finalize: reduce per-block partials in double, write mean ----------
__global__ void arap_finalize(const float* __restrict__ partial,
                              float* __restrict__ out, int NB, double scale) {
    int b = blockIdx.x;
    int t = threadIdx.x;
    double s = 0.0;
    for (int i = t; i < NB; i += blockDim.x)
        s += (double)partial[(size_t)i * 16 + b];
    #pragma unroll
    for (int off = 32; off; off >>= 1) s += __shfl_xor(s, off, 64);
    __shared__ double ws_[THREADS / 64];
    int wave = t >> 6, lane = t & 63;
    if (lane == 0) ws_[wave] = s;
    __syncthreads();
    if (t == 0) {
        double tot = 0.0;
        #pragma unroll
        for (int w = 0; w < THREADS / 64; ++w) tot += ws_[w];
        out[b] = (float)(tot * scale);
    }
}

extern "C" void kernel_launch(void* const* d_in, const int* in_sizes, int n_in,
                              void* d_out, int out_size, void* d_ws, size_t ws_size,
                              hipStream_t stream) {
    const float* dx    = (const float*)d_in[0];   // (B, NV, 3)
    const float* x     = (const float*)d_in[1];   // (B, NV, 3)
    const int*   edges = (const int*)d_in[2];     // (E, 2), sorted, symmetric
    float* out = (float*)d_out;

    int B   = out_size;                 // 16
    long E  = in_sizes[2] / 2;
    int NV  = in_sizes[0] / (B * 3);    // 100000

    // per-wave span, multiple of 4 (keeps int4 edge loads 16B-aligned)
    long spw = (E + NWAVES - 1) / NWAVES;
    spw = (spw + 3) & ~(long)3;

    size_t partial_bytes = ((size_t)MAIN_BLOCKS * 16 * sizeof(float) + 255) & ~(size_t)255;
    size_t ct_bytes      = (size_t)NV * 16 * 6 * sizeof(float);

    float* partial = (float*)d_ws;
    double scale = 2.0 / (double)E;     // j<k only; mirrors are bit-identical

    if (B == 16 && ws_size >= partial_bytes + ct_bytes) {
        float* ct = (float*)((char*)d_ws + partial_bytes);
        arap_transpose<<<(NV + TTV - 1) / TTV, THREADS, 0, stream>>>(x, dx, ct, NV);
        arap_main_fused<<<MAIN_BLOCKS, THREADS, 0, stream>>>(ct, (const int2*)edges,
                                                             partial, E, spw);
        arap_finalize<<<B, THREADS, 0, stream>>>(partial, out, MAIN_BLOCKS, scale);
    } else {
        int ggrid = 2048;
        int chunk = (int)((E + (long)ggrid * 16 - 1) / ((long)ggrid * 16));
        arap_main_generic<<<ggrid, THREADS, 0, stream>>>(x, dx, (const int2*)edges,
                                                         partial, E, chunk, NV, B);
        arap_finalize<<<B, THREADS, 0, stream>>>(partial, out, ggrid, scale);
    }
}